// Round 9
// baseline (521.739 us; speedup 1.0000x reference)
//
#include <hip/hip_runtime.h>
#include <hip/hip_bf16.h>
#include <math.h>

// ---------------------------------------------------------------------------
// GraphSAGE 3-layer, HIDDEN=64, mean aggregation.
// R8: single-read radix-partition CSR build.
//   A: partition_edges -- read edges once, pack (dlo<<17|src), scatter into
//      7 dst-range buckets (range 16384) with ballot-ranked contiguous
//      per-wg chunk writes (no sub-line cross-XCD bouncing).
//   B: count_bucket    -- bucket-local degree count (XCD-pinned via wgid&7).
//   C: fill_bucket     -- bucket-local CSR fill (XCD-pinned).
// Replaces R7's 8-pass filter (250MB traffic -> ~40MB).
// gather_mean / dense_cat / scan unchanged from R6/R7.
// R9: identical resubmit (R8 bench hit GPUAcquisitionTimeout, never ran).
// ---------------------------------------------------------------------------

#define HID 64
#define NB 7          // buckets
#define BSH 14        // bucket range = 16384 nodes
#define BCAP 300000   // slab capacity (expected ~262K, +38K slack)

__device__ __forceinline__ float b2f(unsigned short u) {
    unsigned int t = ((unsigned int)u) << 16;
    return __uint_as_float(t);
}
__device__ __forceinline__ unsigned short f2b(float f) {
    unsigned int u = __float_as_uint(f);
    u = (u + 0x7FFF + ((u >> 16) & 1)) >> 16;   // RNE
    return (unsigned short)u;
}

// ---- pass A: partition edges into dst-range buckets -----------------------

__launch_bounds__(256)
__global__ void partition_edges(const int* __restrict__ src, const int* __restrict__ dst,
                                unsigned int* __restrict__ part, int* __restrict__ bcnt,
                                int E, int CE) {
    __shared__ int wvCnt[4][NB];
    __shared__ int wvOff[4][NB];
    int tid = threadIdx.x, w = tid >> 6, lane = tid & 63;
    int e0 = blockIdx.x * CE, e1 = min(e0 + CE, E);
    if (e0 >= E) return;
    unsigned long long lmask = (1ULL << lane) - 1ULL;

    // loop1: per-wave bucket counts via ballot (lane b accumulates bucket b)
    int acc = 0;
    for (int eb = e0; eb < e1; eb += 256) {
        int e = eb + tid;
        int b = NB;
        if (e < e1) b = dst[e] >> BSH;
#pragma unroll
        for (int bb = 0; bb < NB; ++bb) {
            unsigned long long m = __ballot(b == bb);
            if (lane == bb) acc += __popcll(m);
        }
    }
    if (lane < NB) wvCnt[w][lane] = acc;
    __syncthreads();

    // allocate global bases, compute per-wave absolute offsets
    if (tid < NB) {
        int b = tid;
        int t0 = wvCnt[0][b], t1 = wvCnt[1][b], t2 = wvCnt[2][b], t3 = wvCnt[3][b];
        int rel = atomicAdd(&bcnt[b], t0 + t1 + t2 + t3);
        int base = b * BCAP + rel;
        wvOff[0][b] = base;
        wvOff[1][b] = base + t0;
        wvOff[2][b] = base + t0 + t1;
        wvOff[3][b] = base + t0 + t1 + t2;
    }
    __syncthreads();

    // loop2: ballot-rank within wave, write packed edge
    for (int eb = e0; eb < e1; eb += 256) {
        int e = eb + tid;
        int b = NB, sv = 0, d = 0;
        if (e < e1) { sv = src[e]; d = dst[e]; b = d >> BSH; }
        unsigned long long mymask = 0;
        int myoff = 0;
#pragma unroll
        for (int bb = 0; bb < NB; ++bb) {
            unsigned long long m = __ballot(b == bb);
            if (b == bb) { mymask = m; myoff = wvOff[w][bb]; }
            if (lane == bb) wvCnt[w][bb] = __popcll(m);
        }
        if (b < NB) {
            int pos = myoff + (int)__popcll(mymask & lmask);
            if (pos < (b + 1) * BCAP)
                part[pos] = ((unsigned)(d & ((1 << BSH) - 1)) << 17) | (unsigned)sv;
        }
        if (lane < NB) wvOff[w][lane] += wvCnt[w][lane];
    }
}

// ---- pass B: bucket-local degree count (XCD-pinned) -----------------------

__launch_bounds__(256)
__global__ void count_bucket(const unsigned int* __restrict__ part,
                             const int* __restrict__ bcnt, int* __restrict__ cnt) {
    int s = blockIdx.x & 7;
    if (s >= NB) return;
    int c = blockIdx.x >> 3, M = gridDim.x >> 3;
    int sz = bcnt[s];
    const unsigned int* slab = part + (size_t)s * BCAP;
    int lo = s << BSH;
    for (int i = c * 256 + threadIdx.x; i < sz; i += M * 256) {
        unsigned u = slab[i];
        atomicAdd(&cnt[lo + (int)(u >> 17)], 1);
    }
}

// ---- pass C: bucket-local CSR fill (XCD-pinned) ---------------------------

__launch_bounds__(256)
__global__ void fill_bucket(const unsigned int* __restrict__ part,
                            const int* __restrict__ bcnt, int* __restrict__ cnt,
                            const int* __restrict__ offs, int* __restrict__ csr) {
    int s = blockIdx.x & 7;
    if (s >= NB) return;
    int c = blockIdx.x >> 3, M = gridDim.x >> 3;
    int sz = bcnt[s];
    const unsigned int* slab = part + (size_t)s * BCAP;
    int lo = s << BSH;
    for (int i = c * 256 + threadIdx.x; i < sz; i += M * 256) {
        unsigned u = slab[i];
        int d = lo + (int)(u >> 17);
        int p = atomicSub(&cnt[d], 1) - 1;
        csr[offs[d] + p] = (int)(u & 0x1FFFF);
    }
}

// ---- scan ------------------------------------------------------------------

__global__ void scan_partials(const int* __restrict__ cnt, int* __restrict__ bsum, int n) {
    __shared__ int lsum[256];
    int t = threadIdx.x;
    int base = blockIdx.x * 1024 + t * 4;
    int s = 0;
    if (base + 3 < n) {
        int4 v = *(const int4*)&cnt[base];
        s = v.x + v.y + v.z + v.w;
    } else {
        for (int i = 0; i < 4; ++i) if (base + i < n) s += cnt[base + i];
    }
    lsum[t] = s;
    __syncthreads();
    for (int off = 128; off > 0; off >>= 1) {
        if (t < off) lsum[t] += lsum[t + off];
        __syncthreads();
    }
    if (t == 0) bsum[blockIdx.x] = lsum[0];
}

__global__ void scan_tops(int* __restrict__ bsum, int* __restrict__ offs_last,
                          int nb, int E) {
    __shared__ int s[128];
    int t = threadIdx.x;
    s[t] = (t < nb) ? bsum[t] : 0;
    __syncthreads();
    for (int off = 1; off < 128; off <<= 1) {
        int v = (t >= off) ? s[t - off] : 0;
        __syncthreads();
        s[t] += v;
        __syncthreads();
    }
    if (t < nb) bsum[t] = (t == 0) ? 0 : s[t - 1];
    if (t == 0) *offs_last = E;
}

__global__ void scan_write(const int* __restrict__ cnt, const int* __restrict__ bsum,
                           int* __restrict__ offs, int n) {
    __shared__ int lsum[256];
    int t = threadIdx.x;
    int base = blockIdx.x * 1024 + t * 4;
    int v0 = 0, v1 = 0, v2 = 0, v3 = 0;
    bool full = (base + 3 < n);
    if (full) {
        int4 v = *(const int4*)&cnt[base];
        v0 = v.x; v1 = v.y; v2 = v.z; v3 = v.w;
    } else {
        if (base     < n) v0 = cnt[base];
        if (base + 1 < n) v1 = cnt[base + 1];
        if (base + 2 < n) v2 = cnt[base + 2];
        if (base + 3 < n) v3 = cnt[base + 3];
    }
    lsum[t] = v0 + v1 + v2 + v3;
    __syncthreads();
    for (int off = 1; off < 256; off <<= 1) {
        int u = (t >= off) ? lsum[t - off] : 0;
        __syncthreads();
        lsum[t] += u;
        __syncthreads();
    }
    int ex = bsum[blockIdx.x] + ((t == 0) ? 0 : lsum[t - 1]);
    int o0 = ex, o1 = ex + v0, o2 = o1 + v1, o3 = o2 + v2;
    if (full) {
        *(int4*)&offs[base] = make_int4(o0, o1, o2, o3);
    } else {
        if (base     < n) offs[base]     = o0;
        if (base + 1 < n) offs[base + 1] = o1;
        if (base + 2 < n) offs[base + 2] = o2;
        if (base + 3 < n) offs[base + 3] = o3;
    }
}

// ---- f32 -> bf16 convert --------------------------------------------------

__global__ void to_bf16(const float* __restrict__ in, unsigned short* __restrict__ o, int n4) {
    int i = blockIdx.x * blockDim.x + threadIdx.x;
    if (i < n4) {
        float4 v = ((const float4*)in)[i];
        ushort4 u;
        u.x = f2b(v.x); u.y = f2b(v.y); u.z = f2b(v.z); u.w = f2b(v.w);
        ((ushort4*)o)[i] = u;
    }
}

// ---- gather: agg[n] = mean_{s in N(n)} h_bf16[s] --------------------------

__launch_bounds__(256)
__global__ void gather_mean(const unsigned short* __restrict__ hb,
                            const int* __restrict__ offs, const int* __restrict__ csr,
                            float* __restrict__ agg, int nnodes) {
    int lane = threadIdx.x & 63;
    int wv   = threadIdx.x >> 6;
    int wid  = blockIdx.x * 4 + wv;
    int nw   = gridDim.x * 4;
    for (int n = wid; n < nnodes; n += nw) {
        int beg = offs[n], end = offs[n + 1];
        int deg = end - beg;
        float a0 = 0.f, a1 = 0.f, a2 = 0.f, a3 = 0.f;
        float a4 = 0.f, a5 = 0.f, a6 = 0.f, a7 = 0.f;
        for (int base = beg; base < end; base += 64) {
            int cnt = min(64, end - base);
            int myi = csr[base + min(lane, cnt - 1)];
            int j = 0;
            for (; j + 8 <= cnt; j += 8) {
                int s0 = __shfl(myi, j + 0), s1 = __shfl(myi, j + 1);
                int s2 = __shfl(myi, j + 2), s3 = __shfl(myi, j + 3);
                int s4 = __shfl(myi, j + 4), s5 = __shfl(myi, j + 5);
                int s6 = __shfl(myi, j + 6), s7 = __shfl(myi, j + 7);
                a0 += b2f(hb[(size_t)s0 * HID + lane]);
                a1 += b2f(hb[(size_t)s1 * HID + lane]);
                a2 += b2f(hb[(size_t)s2 * HID + lane]);
                a3 += b2f(hb[(size_t)s3 * HID + lane]);
                a4 += b2f(hb[(size_t)s4 * HID + lane]);
                a5 += b2f(hb[(size_t)s5 * HID + lane]);
                a6 += b2f(hb[(size_t)s6 * HID + lane]);
                a7 += b2f(hb[(size_t)s7 * HID + lane]);
            }
            for (; j < cnt; ++j) {
                int s = __shfl(myi, j);
                a0 += b2f(hb[(size_t)s * HID + lane]);
            }
        }
        float m = (((a0 + a1) + (a2 + a3)) + ((a4 + a5) + (a6 + a7)))
                  * (1.0f / (float)max(deg, 1));
        agg[(size_t)n * HID + lane] = m;
    }
}

// ---- dense: out = elu([agg|h] @ [[Wl];[Wr]] + b) --------------------------

__launch_bounds__(256)
__global__ void dense_cat(const float* __restrict__ agg, const float* __restrict__ h,
                          const float* __restrict__ Wl, const float* __restrict__ bl,
                          const float* __restrict__ Wr, float* __restrict__ out,
                          unsigned short* __restrict__ out_bf, int nrows) {
    __shared__ float W_s[128][64];
    __shared__ float cat_s[32][132];
    __shared__ float bl_s[64];
    int tid = threadIdx.x;
    int n0  = blockIdx.x * 32;

    for (int idx = tid; idx < 2048; idx += 256) {
        int f = idx >> 4, c4 = (idx & 15) * 4;
        const float* Wsrc = (f < 64) ? (Wl + f * 64 + c4) : (Wr + (f - 64) * 64 + c4);
        *(float4*)&W_s[f][c4] = *(const float4*)Wsrc;
    }
    if (tid < 64) bl_s[tid] = bl[tid];

    for (int idx = tid; idx < 1024; idx += 256) {
        int r = idx >> 5, c4 = idx & 31;
        float4 v = make_float4(0.f, 0.f, 0.f, 0.f);
        if (n0 + r < nrows) {
            const float* srcp = (c4 < 16) ? (agg + (size_t)(n0 + r) * HID + c4 * 4)
                                          : (h   + (size_t)(n0 + r) * HID + (c4 - 16) * 4);
            v = *(const float4*)srcp;
        }
        *(float4*)&cat_s[r][c4 * 4] = v;
    }
    __syncthreads();

    int cg = tid & 15, rg = tid >> 4;
    int c0 = cg * 4, r0 = rg * 2;
    float acc0x = 0.f, acc0y = 0.f, acc0z = 0.f, acc0w = 0.f;
    float acc1x = 0.f, acc1y = 0.f, acc1z = 0.f, acc1w = 0.f;

    for (int k = 0; k < 128; k += 4) {
        float4 a0 = *(float4*)&cat_s[r0 + 0][k];
        float4 a1 = *(float4*)&cat_s[r0 + 1][k];
#pragma unroll
        for (int u = 0; u < 4; ++u) {
            float4 w = *(float4*)&W_s[k + u][c0];
            float av0 = (&a0.x)[u], av1 = (&a1.x)[u];
            acc0x += av0 * w.x; acc0y += av0 * w.y;
            acc0z += av0 * w.z; acc0w += av0 * w.w;
            acc1x += av1 * w.x; acc1y += av1 * w.y;
            acc1z += av1 * w.z; acc1w += av1 * w.w;
        }
    }

    float bx = bl_s[c0], by = bl_s[c0 + 1], bz = bl_s[c0 + 2], bw = bl_s[c0 + 3];
#pragma unroll
    for (int i = 0; i < 2; ++i) {
        int row = n0 + r0 + i;
        if (row < nrows) {
            float4 o;
            o.x = (i ? acc1x : acc0x) + bx;
            o.y = (i ? acc1y : acc0y) + by;
            o.z = (i ? acc1z : acc0z) + bz;
            o.w = (i ? acc1w : acc0w) + bw;
            o.x = o.x > 0.f ? o.x : expm1f(o.x);
            o.y = o.y > 0.f ? o.y : expm1f(o.y);
            o.z = o.z > 0.f ? o.z : expm1f(o.z);
            o.w = o.w > 0.f ? o.w : expm1f(o.w);
            *(float4*)&out[(size_t)row * HID + c0] = o;
            if (out_bf) {
                ushort4 u;
                u.x = f2b(o.x); u.y = f2b(o.y); u.z = f2b(o.z); u.w = f2b(o.w);
                *(ushort4*)&out_bf[(size_t)row * HID + c0] = u;
            }
        }
    }
}

// ---- launch ---------------------------------------------------------------

extern "C" void kernel_launch(void* const* d_in, const int* in_sizes, int n_in,
                              void* d_out, int out_size, void* d_ws, size_t ws_size,
                              hipStream_t stream) {
    const float* x   = (const float*)d_in[0];
    const int*   ei  = (const int*)d_in[1];
    const float* Wl1 = (const float*)d_in[2];
    const float* bl1 = (const float*)d_in[3];
    const float* Wr1 = (const float*)d_in[4];
    const float* Wl2 = (const float*)d_in[5];
    const float* bl2 = (const float*)d_in[6];
    const float* Wr2 = (const float*)d_in[7];
    const float* Wl3 = (const float*)d_in[8];
    const float* bl3 = (const float*)d_in[9];
    const float* Wr3 = (const float*)d_in[10];
    float* out = (float*)d_out;

    int N = in_sizes[0] / HID;   // 100000
    int E = in_sizes[1] / 2;     // 1600000
    const int* src = ei;
    const int* dst = ei + E;

    // workspace (~84 MB); part[] overlaps aggb (CSR build finishes first)
    char* p = (char*)d_ws;
    float*          aggb = (float*)p;          p += (size_t)N * HID * sizeof(float);
    float*          H    = (float*)p;          p += (size_t)N * HID * sizeof(float);
    unsigned short* bfA  = (unsigned short*)p; p += (size_t)N * HID * 2;
    unsigned short* bfB  = (unsigned short*)p; p += (size_t)N * HID * 2;
    int*            csr  = (int*)p;            p += (size_t)E * sizeof(int);
    int*            cnt  = (int*)p;            p += (size_t)N * sizeof(int);
    int*            bcnt = (int*)p;            p += 8 * sizeof(int);      // adjacent to cnt
    int*            offs = (int*)p;            p += (size_t)(N + 4) * sizeof(int);
    int*            bsum = (int*)p;            p += 256 * sizeof(int);
    unsigned int*   part = (unsigned int*)aggb;   // 7*BCAP*4 = 8.4MB < 25.6MB

    hipMemsetAsync(cnt, 0, ((size_t)N + 8) * sizeof(int), stream);   // cnt + bcnt

    const int CE = 6272;
    int M  = (E + CE - 1) / CE;               // 256 chunks
    int sb = (N + 1023) / 1024;

    partition_edges<<<M, 256, 0, stream>>>(src, dst, part, bcnt, E, CE);
    count_bucket<<<512, 256, 0, stream>>>(part, bcnt, cnt);
    scan_partials<<<sb, 256, 0, stream>>>(cnt, bsum, N);
    scan_tops<<<1, 128, 0, stream>>>(bsum, &offs[N], sb, E);
    scan_write<<<sb, 256, 0, stream>>>(cnt, bsum, offs, N);
    fill_bucket<<<512, 256, 0, stream>>>(part, bcnt, cnt, offs, csr);

    to_bf16<<<(N * HID / 4 + 255) / 256, 256, 0, stream>>>(x, bfB, N * HID / 4);

    int db = (N + 31) / 32;

    gather_mean<<<2048, 256, 0, stream>>>(bfB, offs, csr, aggb, N);
    dense_cat<<<db, 256, 0, stream>>>(aggb, x, Wl1, bl1, Wr1, H, bfA, N);

    gather_mean<<<2048, 256, 0, stream>>>(bfA, offs, csr, aggb, N);
    dense_cat<<<db, 256, 0, stream>>>(aggb, H, Wl2, bl2, Wr2, H, bfB, N);

    gather_mean<<<2048, 256, 0, stream>>>(bfB, offs, csr, aggb, N);
    dense_cat<<<db, 256, 0, stream>>>(aggb, H, Wl3, bl3, Wr3, out, (unsigned short*)nullptr, N);
}

// Round 11
// 445.007 us; speedup vs baseline: 1.1724x; 1.1724x over previous
//
#include <hip/hip_runtime.h>
#include <hip/hip_bf16.h>
#include <math.h>

// ---------------------------------------------------------------------------
// GraphSAGE 3-layer, HIDDEN=64, mean aggregation.
// R10: (a) coalesced-store CSR build -- R9 proved scattered 4B stores cost
// ~45B HBM writeback EACH regardless of L2 residency/pinning (71MB for 6.4MB
// payload). New build: LDS-staged partition into 512-node sub-buckets
// (contiguous run writes) -> per-sub LDS histogram (coalesced cnt writes) ->
// per-sub LDS counting sort (one contiguous csr slab write). Every store
// coalesced. (b) bf16 inter-layer: gather writes bf16 agg, dense reads bf16
// agg/h + writes bf16 only (f32 H buffer gone; final layer writes f32 out).
// R11: identical resubmit (R10 bench: container failed twice -- infra).
// ---------------------------------------------------------------------------

#define HID   64
#define SB    512        // nodes per sub-bucket
#define MAXSB 256        // LDS counter array size (>= nsb=196)
#define SCAP  10240      // per-sub slab capacity (mean 8192, sigma~90)
#define CHUNK 8192       // edges per partition wg

__device__ __forceinline__ float b2f(unsigned short u) {
    unsigned int t = ((unsigned int)u) << 16;
    return __uint_as_float(t);
}
__device__ __forceinline__ unsigned short f2b(float f) {
    unsigned int u = __float_as_uint(f);
    u = (u + 0x7FFF + ((u >> 16) & 1)) >> 16;   // RNE
    return (unsigned short)u;
}

// ---- pass A: partition edges into 512-node sub-buckets (coalesced runs) ---

__launch_bounds__(256)
__global__ void partition_edges(const int* __restrict__ src, const int* __restrict__ dst,
                                unsigned int* __restrict__ part, int* __restrict__ gcnt,
                                int E) {
    __shared__ unsigned int stage[CHUNK];   // 32 KB
    __shared__ int lcnt[MAXSB];
    __shared__ int lbase[MAXSB];
    __shared__ int lrun[MAXSB];
    __shared__ int gpos[MAXSB];
    __shared__ int tmp[MAXSB];
    int tid = threadIdx.x;
    int e0 = blockIdx.x * CHUNK, e1 = min(e0 + CHUNK, E);

    lcnt[tid] = 0;
    __syncthreads();
    // phase 1: local histogram by sub-bucket
    for (int e = e0 + tid; e < e1; e += 256)
        atomicAdd(&lcnt[dst[e] >> 9], 1);
    __syncthreads();
    // exclusive scan of lcnt (256 wide)
    int v = lcnt[tid];
    tmp[tid] = v;
    __syncthreads();
    for (int off = 1; off < 256; off <<= 1) {
        int u = (tid >= off) ? tmp[tid - off] : 0;
        __syncthreads();
        tmp[tid] += u;
        __syncthreads();
    }
    lbase[tid] = tmp[tid] - v;
    lrun[tid]  = tmp[tid] - v;
    __syncthreads();
    // phase 2: place into LDS stage ordered by sub-bucket
    for (int e = e0 + tid; e < e1; e += 256) {
        int d = dst[e];
        int s = d >> 9;
        int pos = atomicAdd(&lrun[s], 1);
        stage[pos] = ((unsigned)(d & 511) << 17) | (unsigned)src[e];
    }
    __syncthreads();
    // phase 3: allocate global slab space
    {
        int c = lcnt[tid];
        gpos[tid] = c ? atomicAdd(&gcnt[tid], c) : 0;
    }
    __syncthreads();
    // phase 4: contiguous run writes per sub-bucket
    for (int s = 0; s < MAXSB; ++s) {
        int c = lcnt[s];
        if (c == 0) continue;
        int gp = gpos[s];
        int c2 = min(c, max(SCAP - gp, 0));
        unsigned int* dp = part + (size_t)s * SCAP + gp;
        const unsigned int* sp = &stage[lbase[s]];
        for (int j = tid; j < c2; j += 256) dp[j] = sp[j];
    }
}

// ---- pass B: per-sub-bucket degree histogram, coalesced cnt write ---------

__launch_bounds__(256)
__global__ void sub_count(const unsigned int* __restrict__ part,
                          const int* __restrict__ gcnt, int* __restrict__ cnt, int N) {
    __shared__ int lcnt[SB];
    int s = blockIdx.x;
    int sz = min(gcnt[s], SCAP);
    const unsigned int* slab = part + (size_t)s * SCAP;
    for (int i = threadIdx.x; i < SB; i += 256) lcnt[i] = 0;
    __syncthreads();
    for (int i = threadIdx.x; i < sz; i += 256)
        atomicAdd(&lcnt[slab[i] >> 17], 1);
    __syncthreads();
    int base = s * SB;
    for (int i = threadIdx.x; i < SB; i += 256)
        if (base + i < N) cnt[base + i] = lcnt[i];
}

// ---- pass C: per-sub-bucket counting sort, one contiguous csr write -------

__launch_bounds__(256)
__global__ void sub_fill(const unsigned int* __restrict__ part,
                         const int* __restrict__ gcnt, const int* __restrict__ offs,
                         int* __restrict__ csr, int N) {
    __shared__ unsigned int stage[SCAP];   // 40 KB
    __shared__ int lrun[SB];
    int s = blockIdx.x;
    int sz = min(gcnt[s], SCAP);
    const unsigned int* slab = part + (size_t)s * SCAP;
    int base = s * SB;
    int gbase = offs[base];
    for (int i = threadIdx.x; i < SB; i += 256) {
        int node = base + i;
        lrun[i] = offs[min(node, N)] - gbase;
    }
    __syncthreads();
    for (int i = threadIdx.x; i < sz; i += 256) {
        unsigned int u = slab[i];
        int pos = atomicAdd(&lrun[u >> 17], 1);
        stage[pos] = u & 0x1FFFF;
    }
    __syncthreads();
    int total = offs[min(base + SB, N)] - gbase;
    for (int j = threadIdx.x; j < total; j += 256)
        csr[gbase + j] = (int)stage[j];
}

// ---- scan (cnt -> offs) ----------------------------------------------------

__global__ void scan_partials(const int* __restrict__ cnt, int* __restrict__ bsum, int n) {
    __shared__ int lsum[256];
    int t = threadIdx.x;
    int base = blockIdx.x * 1024 + t * 4;
    int s = 0;
    if (base + 3 < n) {
        int4 v = *(const int4*)&cnt[base];
        s = v.x + v.y + v.z + v.w;
    } else {
        for (int i = 0; i < 4; ++i) if (base + i < n) s += cnt[base + i];
    }
    lsum[t] = s;
    __syncthreads();
    for (int off = 128; off > 0; off >>= 1) {
        if (t < off) lsum[t] += lsum[t + off];
        __syncthreads();
    }
    if (t == 0) bsum[blockIdx.x] = lsum[0];
}

__global__ void scan_tops(int* __restrict__ bsum, int* __restrict__ offs_last,
                          int nb, int E) {
    __shared__ int s[128];
    int t = threadIdx.x;
    s[t] = (t < nb) ? bsum[t] : 0;
    __syncthreads();
    for (int off = 1; off < 128; off <<= 1) {
        int v = (t >= off) ? s[t - off] : 0;
        __syncthreads();
        s[t] += v;
        __syncthreads();
    }
    if (t < nb) bsum[t] = (t == 0) ? 0 : s[t - 1];
    if (t == 0) *offs_last = E;
}

__global__ void scan_write(const int* __restrict__ cnt, const int* __restrict__ bsum,
                           int* __restrict__ offs, int n) {
    __shared__ int lsum[256];
    int t = threadIdx.x;
    int base = blockIdx.x * 1024 + t * 4;
    int v0 = 0, v1 = 0, v2 = 0, v3 = 0;
    bool full = (base + 3 < n);
    if (full) {
        int4 v = *(const int4*)&cnt[base];
        v0 = v.x; v1 = v.y; v2 = v.z; v3 = v.w;
    } else {
        if (base     < n) v0 = cnt[base];
        if (base + 1 < n) v1 = cnt[base + 1];
        if (base + 2 < n) v2 = cnt[base + 2];
        if (base + 3 < n) v3 = cnt[base + 3];
    }
    lsum[t] = v0 + v1 + v2 + v3;
    __syncthreads();
    for (int off = 1; off < 256; off <<= 1) {
        int u = (t >= off) ? lsum[t - off] : 0;
        __syncthreads();
        lsum[t] += u;
        __syncthreads();
    }
    int ex = bsum[blockIdx.x] + ((t == 0) ? 0 : lsum[t - 1]);
    int o0 = ex, o1 = ex + v0, o2 = o1 + v1, o3 = o2 + v2;
    if (full) {
        *(int4*)&offs[base] = make_int4(o0, o1, o2, o3);
    } else {
        if (base     < n) offs[base]     = o0;
        if (base + 1 < n) offs[base + 1] = o1;
        if (base + 2 < n) offs[base + 2] = o2;
        if (base + 3 < n) offs[base + 3] = o3;
    }
}

// ---- f32 -> bf16 convert --------------------------------------------------

__global__ void to_bf16(const float* __restrict__ in, unsigned short* __restrict__ o, int n4) {
    int i = blockIdx.x * blockDim.x + threadIdx.x;
    if (i < n4) {
        float4 v = ((const float4*)in)[i];
        ushort4 u;
        u.x = f2b(v.x); u.y = f2b(v.y); u.z = f2b(v.z); u.w = f2b(v.w);
        ((ushort4*)o)[i] = u;
    }
}

// ---- gather: agg[n] = mean_{s in N(n)} h_bf16[s]  (bf16 out) --------------

__launch_bounds__(256)
__global__ void gather_mean(const unsigned short* __restrict__ hb,
                            const int* __restrict__ offs, const int* __restrict__ csr,
                            unsigned short* __restrict__ agg, int nnodes) {
    int lane = threadIdx.x & 63;
    int wv   = threadIdx.x >> 6;
    int wid  = blockIdx.x * 4 + wv;
    int nw   = gridDim.x * 4;
    for (int n = wid; n < nnodes; n += nw) {
        int beg = offs[n], end = offs[n + 1];
        int deg = end - beg;
        float a0 = 0.f, a1 = 0.f, a2 = 0.f, a3 = 0.f;
        float a4 = 0.f, a5 = 0.f, a6 = 0.f, a7 = 0.f;
        for (int base = beg; base < end; base += 64) {
            int cnt = min(64, end - base);
            int myi = csr[base + min(lane, cnt - 1)];
            int j = 0;
            for (; j + 8 <= cnt; j += 8) {
                int s0 = __shfl(myi, j + 0), s1 = __shfl(myi, j + 1);
                int s2 = __shfl(myi, j + 2), s3 = __shfl(myi, j + 3);
                int s4 = __shfl(myi, j + 4), s5 = __shfl(myi, j + 5);
                int s6 = __shfl(myi, j + 6), s7 = __shfl(myi, j + 7);
                a0 += b2f(hb[(size_t)s0 * HID + lane]);
                a1 += b2f(hb[(size_t)s1 * HID + lane]);
                a2 += b2f(hb[(size_t)s2 * HID + lane]);
                a3 += b2f(hb[(size_t)s3 * HID + lane]);
                a4 += b2f(hb[(size_t)s4 * HID + lane]);
                a5 += b2f(hb[(size_t)s5 * HID + lane]);
                a6 += b2f(hb[(size_t)s6 * HID + lane]);
                a7 += b2f(hb[(size_t)s7 * HID + lane]);
            }
            for (; j < cnt; ++j) {
                int s = __shfl(myi, j);
                a0 += b2f(hb[(size_t)s * HID + lane]);
            }
        }
        float m = (((a0 + a1) + (a2 + a3)) + ((a4 + a5) + (a6 + a7)))
                  * (1.0f / (float)max(deg, 1));
        agg[(size_t)n * HID + lane] = f2b(m);
    }
}

// ---- dense: out = elu([agg|h] @ [[Wl];[Wr]] + b), bf16 in, bf16/f32 out ---

__launch_bounds__(256)
__global__ void dense_cat(const unsigned short* __restrict__ aggb,
                          const unsigned short* __restrict__ hb,
                          const float* __restrict__ Wl, const float* __restrict__ bl,
                          const float* __restrict__ Wr,
                          float* __restrict__ outf, unsigned short* __restrict__ out_bf,
                          int nrows) {
    __shared__ float W_s[128][64];     // 32 KB
    __shared__ float cat_s[32][132];   // 16.9 KB
    __shared__ float bl_s[64];
    int tid = threadIdx.x;
    int n0  = blockIdx.x * 32;

    for (int idx = tid; idx < 2048; idx += 256) {
        int f = idx >> 4, c4 = (idx & 15) * 4;
        const float* Wsrc = (f < 64) ? (Wl + f * 64 + c4) : (Wr + (f - 64) * 64 + c4);
        *(float4*)&W_s[f][c4] = *(const float4*)Wsrc;
    }
    if (tid < 64) bl_s[tid] = bl[tid];

    // stage cat rows from bf16 (agg cols 0..63, h cols 64..127)
    for (int idx = tid; idx < 1024; idx += 256) {
        int r = idx >> 5, c4 = idx & 31;
        float4 v = make_float4(0.f, 0.f, 0.f, 0.f);
        if (n0 + r < nrows) {
            const unsigned short* sp = (c4 < 16)
                ? (aggb + (size_t)(n0 + r) * HID + c4 * 4)
                : (hb   + (size_t)(n0 + r) * HID + (c4 - 16) * 4);
            ushort4 u = *(const ushort4*)sp;
            v = make_float4(b2f(u.x), b2f(u.y), b2f(u.z), b2f(u.w));
        }
        *(float4*)&cat_s[r][c4 * 4] = v;
    }
    __syncthreads();

    int cg = tid & 15, rg = tid >> 4;
    int c0 = cg * 4, r0 = rg * 2;
    float acc0x = 0.f, acc0y = 0.f, acc0z = 0.f, acc0w = 0.f;
    float acc1x = 0.f, acc1y = 0.f, acc1z = 0.f, acc1w = 0.f;

    for (int k = 0; k < 128; k += 4) {
        float4 a0 = *(float4*)&cat_s[r0 + 0][k];
        float4 a1 = *(float4*)&cat_s[r0 + 1][k];
#pragma unroll
        for (int u = 0; u < 4; ++u) {
            float4 w = *(float4*)&W_s[k + u][c0];
            float av0 = (&a0.x)[u], av1 = (&a1.x)[u];
            acc0x += av0 * w.x; acc0y += av0 * w.y;
            acc0z += av0 * w.z; acc0w += av0 * w.w;
            acc1x += av1 * w.x; acc1y += av1 * w.y;
            acc1z += av1 * w.z; acc1w += av1 * w.w;
        }
    }

    float bx = bl_s[c0], by = bl_s[c0 + 1], bz = bl_s[c0 + 2], bw = bl_s[c0 + 3];
#pragma unroll
    for (int i = 0; i < 2; ++i) {
        int row = n0 + r0 + i;
        if (row < nrows) {
            float4 o;
            o.x = (i ? acc1x : acc0x) + bx;
            o.y = (i ? acc1y : acc0y) + by;
            o.z = (i ? acc1z : acc0z) + bz;
            o.w = (i ? acc1w : acc0w) + bw;
            o.x = o.x > 0.f ? o.x : expm1f(o.x);
            o.y = o.y > 0.f ? o.y : expm1f(o.y);
            o.z = o.z > 0.f ? o.z : expm1f(o.z);
            o.w = o.w > 0.f ? o.w : expm1f(o.w);
            if (outf) *(float4*)&outf[(size_t)row * HID + c0] = o;
            if (out_bf) {
                ushort4 u;
                u.x = f2b(o.x); u.y = f2b(o.y); u.z = f2b(o.z); u.w = f2b(o.w);
                *(ushort4*)&out_bf[(size_t)row * HID + c0] = u;
            }
        }
    }
}

// ---- launch ---------------------------------------------------------------

extern "C" void kernel_launch(void* const* d_in, const int* in_sizes, int n_in,
                              void* d_out, int out_size, void* d_ws, size_t ws_size,
                              hipStream_t stream) {
    const float* x   = (const float*)d_in[0];
    const int*   ei  = (const int*)d_in[1];
    const float* Wl1 = (const float*)d_in[2];
    const float* bl1 = (const float*)d_in[3];
    const float* Wr1 = (const float*)d_in[4];
    const float* Wl2 = (const float*)d_in[5];
    const float* bl2 = (const float*)d_in[6];
    const float* Wr2 = (const float*)d_in[7];
    const float* Wl3 = (const float*)d_in[8];
    const float* bl3 = (const float*)d_in[9];
    const float* Wr3 = (const float*)d_in[10];
    float* out = (float*)d_out;

    int N = in_sizes[0] / HID;   // 100000
    int E = in_sizes[1] / 2;     // 1600000
    const int* src = ei;
    const int* dst = ei + E;

    int nsb = (N + SB - 1) / SB;          // 196 sub-buckets
    int PB  = (E + CHUNK - 1) / CHUNK;    // 196 partition wgs
    int sb  = (N + 1023) / 1024;          // 98 scan blocks

    // workspace (~67 MB)
    char* p = (char*)d_ws;
    unsigned short* aggB = (unsigned short*)p; p += (size_t)N * HID * 2;       // 12.8
    unsigned short* bfX  = (unsigned short*)p; p += (size_t)N * HID * 2;       // 12.8
    unsigned short* bf1  = (unsigned short*)p; p += (size_t)N * HID * 2;       // 12.8
    unsigned short* bf2  = (unsigned short*)p; p += (size_t)N * HID * 2;       // 12.8
    int*            csr  = (int*)p;            p += (size_t)E * sizeof(int);   // 6.4
    int*            cnt  = (int*)p;            p += (size_t)N * sizeof(int);
    int*            offs = (int*)p;            p += (size_t)(N + 4) * sizeof(int);
    int*            bsum = (int*)p;            p += 256 * sizeof(int);
    int*            gcnt = (int*)p;            p += MAXSB * sizeof(int);
    unsigned int*   part = (unsigned int*)p;   p += (size_t)MAXSB * SCAP * 4;  // 10.5

    hipMemsetAsync(gcnt, 0, MAXSB * sizeof(int), stream);   // only gcnt needs zeroing

    partition_edges<<<PB, 256, 0, stream>>>(src, dst, part, gcnt, E);
    sub_count<<<nsb, 256, 0, stream>>>(part, gcnt, cnt, N);
    scan_partials<<<sb, 256, 0, stream>>>(cnt, bsum, N);
    scan_tops<<<1, 128, 0, stream>>>(bsum, &offs[N], sb, E);
    scan_write<<<sb, 256, 0, stream>>>(cnt, bsum, offs, N);
    sub_fill<<<nsb, 256, 0, stream>>>(part, gcnt, offs, csr, N);

    to_bf16<<<(N * HID / 4 + 255) / 256, 256, 0, stream>>>(x, bfX, N * HID / 4);

    int db = (N + 31) / 32;

    gather_mean<<<2048, 256, 0, stream>>>(bfX, offs, csr, aggB, N);
    dense_cat<<<db, 256, 0, stream>>>(aggB, bfX, Wl1, bl1, Wr1, (float*)nullptr, bf1, N);

    gather_mean<<<2048, 256, 0, stream>>>(bf1, offs, csr, aggB, N);
    dense_cat<<<db, 256, 0, stream>>>(aggB, bf1, Wl2, bl2, Wr2, (float*)nullptr, bf2, N);

    gather_mean<<<2048, 256, 0, stream>>>(bf2, offs, csr, aggB, N);
    dense_cat<<<db, 256, 0, stream>>>(aggB, bf2, Wl3, bl3, Wr3, out, (unsigned short*)nullptr, N);
}

// Round 12
// 403.993 us; speedup vs baseline: 1.2915x; 1.1015x over previous
//
#include <hip/hip_runtime.h>
#include <hip/hip_bf16.h>
#include <math.h>

// ---------------------------------------------------------------------------
// GraphSAGE 3-layer, HIDDEN=64, mean aggregation.
// R12: parallelize partition_edges (was 82us, occupancy 6.6%, 196 blocks on
// 256 CUs + serial per-bucket copy loop).
//   - CHUNK 8192 -> 2048: 782 blocks (~3/CU).
//   - phase 4 fully parallel via sbkt[] (bucket id per staged slot).
//   - shfl-based scan (6 syncthreads total vs 16+).
// Traffic already near-ideal after R10 (7.3MB write); this attacks latency.
// sub_count / sub_fill / scan / gather_mean / dense_cat unchanged.
// ---------------------------------------------------------------------------

#define HID   64
#define SB    512        // nodes per sub-bucket
#define MAXSB 256        // counter array size (>= nsb=196)
#define SCAP  10240      // per-sub slab capacity (mean 8163)
#define CHUNK 2048       // edges per partition wg

__device__ __forceinline__ float b2f(unsigned short u) {
    unsigned int t = ((unsigned int)u) << 16;
    return __uint_as_float(t);
}
__device__ __forceinline__ unsigned short f2b(float f) {
    unsigned int u = __float_as_uint(f);
    u = (u + 0x7FFF + ((u >> 16) & 1)) >> 16;   // RNE
    return (unsigned short)u;
}

// ---- pass A: partition edges into 512-node sub-buckets --------------------

__launch_bounds__(256)
__global__ void partition_edges(const int* __restrict__ src, const int* __restrict__ dst,
                                unsigned int* __restrict__ part, int* __restrict__ gcnt,
                                int E) {
    __shared__ unsigned int stage[CHUNK];       // 8 KB
    __shared__ unsigned char sbkt[CHUNK];       // 2 KB
    __shared__ int lcnt[MAXSB];
    __shared__ int lbase[MAXSB];
    __shared__ int lrun[MAXSB];
    __shared__ int gpos[MAXSB];
    __shared__ int wtot[4];
    int tid = threadIdx.x, w = tid >> 6, lane = tid & 63;
    int e0 = blockIdx.x * CHUNK, e1 = min(e0 + CHUNK, E);
    int ne = e1 - e0;
    if (ne <= 0) return;

    lcnt[tid] = 0;
    __syncthreads();
    // phase 1: histogram by sub-bucket (8 edges/thread)
    for (int e = e0 + tid; e < e1; e += 256)
        atomicAdd(&lcnt[dst[e] >> 9], 1);
    __syncthreads();
    // phase 1b: exclusive scan of lcnt via shfl (wave scan + wave-total combine)
    {
        int orig = lcnt[tid];
        int v = orig;
#pragma unroll
        for (int off = 1; off < 64; off <<= 1) {
            int u = __shfl_up(v, off);
            if (lane >= off) v += u;
        }
        if (lane == 63) wtot[w] = v;
        __syncthreads();
        int woff = 0;
        for (int i = 0; i < w; ++i) woff += wtot[i];
        int excl = v + woff - orig;
        lbase[tid] = excl;
        lrun[tid]  = excl;
    }
    __syncthreads();
    // phase 2: place into LDS stage ordered by sub-bucket, record bucket id
    for (int e = e0 + tid; e < e1; e += 256) {
        int d = dst[e];
        int s = d >> 9;
        int pos = atomicAdd(&lrun[s], 1);
        stage[pos] = ((unsigned)(d & 511) << 17) | (unsigned)src[e];
        sbkt[pos]  = (unsigned char)s;
    }
    __syncthreads();
    // phase 3: allocate global slab space
    {
        int c = lcnt[tid];
        gpos[tid] = c ? atomicAdd(&gcnt[tid], c) : 0;
    }
    __syncthreads();
    // phase 4: fully parallel writes (runs of ~10 stay contiguous)
    for (int j = tid; j < ne; j += 256) {
        int s = sbkt[j];
        int gp = gpos[s] + (j - lbase[s]);
        if (gp < SCAP) part[(size_t)s * SCAP + gp] = stage[j];
    }
}

// ---- pass B: per-sub-bucket degree histogram, coalesced cnt write ---------

__launch_bounds__(256)
__global__ void sub_count(const unsigned int* __restrict__ part,
                          const int* __restrict__ gcnt, int* __restrict__ cnt, int N) {
    __shared__ int lcnt[SB];
    int s = blockIdx.x;
    int sz = min(gcnt[s], SCAP);
    const unsigned int* slab = part + (size_t)s * SCAP;
    for (int i = threadIdx.x; i < SB; i += 256) lcnt[i] = 0;
    __syncthreads();
    for (int i = threadIdx.x; i < sz; i += 256)
        atomicAdd(&lcnt[slab[i] >> 17], 1);
    __syncthreads();
    int base = s * SB;
    for (int i = threadIdx.x; i < SB; i += 256)
        if (base + i < N) cnt[base + i] = lcnt[i];
}

// ---- pass C: per-sub-bucket counting sort, one contiguous csr write -------

__launch_bounds__(256)
__global__ void sub_fill(const unsigned int* __restrict__ part,
                         const int* __restrict__ gcnt, const int* __restrict__ offs,
                         int* __restrict__ csr, int N) {
    __shared__ unsigned int stage[SCAP];   // 40 KB
    __shared__ int lrun[SB];
    int s = blockIdx.x;
    int sz = min(gcnt[s], SCAP);
    const unsigned int* slab = part + (size_t)s * SCAP;
    int base = s * SB;
    int gbase = offs[base];
    for (int i = threadIdx.x; i < SB; i += 256) {
        int node = base + i;
        lrun[i] = offs[min(node, N)] - gbase;
    }
    __syncthreads();
    for (int i = threadIdx.x; i < sz; i += 256) {
        unsigned int u = slab[i];
        int pos = atomicAdd(&lrun[u >> 17], 1);
        stage[pos] = u & 0x1FFFF;
    }
    __syncthreads();
    int total = offs[min(base + SB, N)] - gbase;
    for (int j = threadIdx.x; j < total; j += 256)
        csr[gbase + j] = (int)stage[j];
}

// ---- scan (cnt -> offs) ----------------------------------------------------

__global__ void scan_partials(const int* __restrict__ cnt, int* __restrict__ bsum, int n) {
    __shared__ int lsum[256];
    int t = threadIdx.x;
    int base = blockIdx.x * 1024 + t * 4;
    int s = 0;
    if (base + 3 < n) {
        int4 v = *(const int4*)&cnt[base];
        s = v.x + v.y + v.z + v.w;
    } else {
        for (int i = 0; i < 4; ++i) if (base + i < n) s += cnt[base + i];
    }
    lsum[t] = s;
    __syncthreads();
    for (int off = 128; off > 0; off >>= 1) {
        if (t < off) lsum[t] += lsum[t + off];
        __syncthreads();
    }
    if (t == 0) bsum[blockIdx.x] = lsum[0];
}

__global__ void scan_tops(int* __restrict__ bsum, int* __restrict__ offs_last,
                          int nb, int E) {
    __shared__ int s[128];
    int t = threadIdx.x;
    s[t] = (t < nb) ? bsum[t] : 0;
    __syncthreads();
    for (int off = 1; off < 128; off <<= 1) {
        int v = (t >= off) ? s[t - off] : 0;
        __syncthreads();
        s[t] += v;
        __syncthreads();
    }
    if (t < nb) bsum[t] = (t == 0) ? 0 : s[t - 1];
    if (t == 0) *offs_last = E;
}

__global__ void scan_write(const int* __restrict__ cnt, const int* __restrict__ bsum,
                           int* __restrict__ offs, int n) {
    __shared__ int lsum[256];
    int t = threadIdx.x;
    int base = blockIdx.x * 1024 + t * 4;
    int v0 = 0, v1 = 0, v2 = 0, v3 = 0;
    bool full = (base + 3 < n);
    if (full) {
        int4 v = *(const int4*)&cnt[base];
        v0 = v.x; v1 = v.y; v2 = v.z; v3 = v.w;
    } else {
        if (base     < n) v0 = cnt[base];
        if (base + 1 < n) v1 = cnt[base + 1];
        if (base + 2 < n) v2 = cnt[base + 2];
        if (base + 3 < n) v3 = cnt[base + 3];
    }
    lsum[t] = v0 + v1 + v2 + v3;
    __syncthreads();
    for (int off = 1; off < 256; off <<= 1) {
        int u = (t >= off) ? lsum[t - off] : 0;
        __syncthreads();
        lsum[t] += u;
        __syncthreads();
    }
    int ex = bsum[blockIdx.x] + ((t == 0) ? 0 : lsum[t - 1]);
    int o0 = ex, o1 = ex + v0, o2 = o1 + v1, o3 = o2 + v2;
    if (full) {
        *(int4*)&offs[base] = make_int4(o0, o1, o2, o3);
    } else {
        if (base     < n) offs[base]     = o0;
        if (base + 1 < n) offs[base + 1] = o1;
        if (base + 2 < n) offs[base + 2] = o2;
        if (base + 3 < n) offs[base + 3] = o3;
    }
}

// ---- f32 -> bf16 convert --------------------------------------------------

__global__ void to_bf16(const float* __restrict__ in, unsigned short* __restrict__ o, int n4) {
    int i = blockIdx.x * blockDim.x + threadIdx.x;
    if (i < n4) {
        float4 v = ((const float4*)in)[i];
        ushort4 u;
        u.x = f2b(v.x); u.y = f2b(v.y); u.z = f2b(v.z); u.w = f2b(v.w);
        ((ushort4*)o)[i] = u;
    }
}

// ---- gather: agg[n] = mean_{s in N(n)} h_bf16[s]  (bf16 out) --------------

__launch_bounds__(256)
__global__ void gather_mean(const unsigned short* __restrict__ hb,
                            const int* __restrict__ offs, const int* __restrict__ csr,
                            unsigned short* __restrict__ agg, int nnodes) {
    int lane = threadIdx.x & 63;
    int wv   = threadIdx.x >> 6;
    int wid  = blockIdx.x * 4 + wv;
    int nw   = gridDim.x * 4;
    for (int n = wid; n < nnodes; n += nw) {
        int beg = offs[n], end = offs[n + 1];
        int deg = end - beg;
        float a0 = 0.f, a1 = 0.f, a2 = 0.f, a3 = 0.f;
        float a4 = 0.f, a5 = 0.f, a6 = 0.f, a7 = 0.f;
        for (int base = beg; base < end; base += 64) {
            int cnt = min(64, end - base);
            int myi = csr[base + min(lane, cnt - 1)];
            int j = 0;
            for (; j + 8 <= cnt; j += 8) {
                int s0 = __shfl(myi, j + 0), s1 = __shfl(myi, j + 1);
                int s2 = __shfl(myi, j + 2), s3 = __shfl(myi, j + 3);
                int s4 = __shfl(myi, j + 4), s5 = __shfl(myi, j + 5);
                int s6 = __shfl(myi, j + 6), s7 = __shfl(myi, j + 7);
                a0 += b2f(hb[(size_t)s0 * HID + lane]);
                a1 += b2f(hb[(size_t)s1 * HID + lane]);
                a2 += b2f(hb[(size_t)s2 * HID + lane]);
                a3 += b2f(hb[(size_t)s3 * HID + lane]);
                a4 += b2f(hb[(size_t)s4 * HID + lane]);
                a5 += b2f(hb[(size_t)s5 * HID + lane]);
                a6 += b2f(hb[(size_t)s6 * HID + lane]);
                a7 += b2f(hb[(size_t)s7 * HID + lane]);
            }
            for (; j < cnt; ++j) {
                int s = __shfl(myi, j);
                a0 += b2f(hb[(size_t)s * HID + lane]);
            }
        }
        float m = (((a0 + a1) + (a2 + a3)) + ((a4 + a5) + (a6 + a7)))
                  * (1.0f / (float)max(deg, 1));
        agg[(size_t)n * HID + lane] = f2b(m);
    }
}

// ---- dense: out = elu([agg|h] @ [[Wl];[Wr]] + b), bf16 in, bf16/f32 out ---

__launch_bounds__(256)
__global__ void dense_cat(const unsigned short* __restrict__ aggb,
                          const unsigned short* __restrict__ hb,
                          const float* __restrict__ Wl, const float* __restrict__ bl,
                          const float* __restrict__ Wr,
                          float* __restrict__ outf, unsigned short* __restrict__ out_bf,
                          int nrows) {
    __shared__ float W_s[128][64];     // 32 KB
    __shared__ float cat_s[32][132];   // 16.9 KB
    __shared__ float bl_s[64];
    int tid = threadIdx.x;
    int n0  = blockIdx.x * 32;

    for (int idx = tid; idx < 2048; idx += 256) {
        int f = idx >> 4, c4 = (idx & 15) * 4;
        const float* Wsrc = (f < 64) ? (Wl + f * 64 + c4) : (Wr + (f - 64) * 64 + c4);
        *(float4*)&W_s[f][c4] = *(const float4*)Wsrc;
    }
    if (tid < 64) bl_s[tid] = bl[tid];

    // stage cat rows from bf16 (agg cols 0..63, h cols 64..127)
    for (int idx = tid; idx < 1024; idx += 256) {
        int r = idx >> 5, c4 = idx & 31;
        float4 v = make_float4(0.f, 0.f, 0.f, 0.f);
        if (n0 + r < nrows) {
            const unsigned short* sp = (c4 < 16)
                ? (aggb + (size_t)(n0 + r) * HID + c4 * 4)
                : (hb   + (size_t)(n0 + r) * HID + (c4 - 16) * 4);
            ushort4 u = *(const ushort4*)sp;
            v = make_float4(b2f(u.x), b2f(u.y), b2f(u.z), b2f(u.w));
        }
        *(float4*)&cat_s[r][c4 * 4] = v;
    }
    __syncthreads();

    int cg = tid & 15, rg = tid >> 4;
    int c0 = cg * 4, r0 = rg * 2;
    float acc0x = 0.f, acc0y = 0.f, acc0z = 0.f, acc0w = 0.f;
    float acc1x = 0.f, acc1y = 0.f, acc1z = 0.f, acc1w = 0.f;

    for (int k = 0; k < 128; k += 4) {
        float4 a0 = *(float4*)&cat_s[r0 + 0][k];
        float4 a1 = *(float4*)&cat_s[r0 + 1][k];
#pragma unroll
        for (int u = 0; u < 4; ++u) {
            float4 w = *(float4*)&W_s[k + u][c0];
            float av0 = (&a0.x)[u], av1 = (&a1.x)[u];
            acc0x += av0 * w.x; acc0y += av0 * w.y;
            acc0z += av0 * w.z; acc0w += av0 * w.w;
            acc1x += av1 * w.x; acc1y += av1 * w.y;
            acc1z += av1 * w.z; acc1w += av1 * w.w;
        }
    }

    float bx = bl_s[c0], by = bl_s[c0 + 1], bz = bl_s[c0 + 2], bw = bl_s[c0 + 3];
#pragma unroll
    for (int i = 0; i < 2; ++i) {
        int row = n0 + r0 + i;
        if (row < nrows) {
            float4 o;
            o.x = (i ? acc1x : acc0x) + bx;
            o.y = (i ? acc1y : acc0y) + by;
            o.z = (i ? acc1z : acc0z) + bz;
            o.w = (i ? acc1w : acc0w) + bw;
            o.x = o.x > 0.f ? o.x : expm1f(o.x);
            o.y = o.y > 0.f ? o.y : expm1f(o.y);
            o.z = o.z > 0.f ? o.z : expm1f(o.z);
            o.w = o.w > 0.f ? o.w : expm1f(o.w);
            if (outf) *(float4*)&outf[(size_t)row * HID + c0] = o;
            if (out_bf) {
                ushort4 u;
                u.x = f2b(o.x); u.y = f2b(o.y); u.z = f2b(o.z); u.w = f2b(o.w);
                *(ushort4*)&out_bf[(size_t)row * HID + c0] = u;
            }
        }
    }
}

// ---- launch ---------------------------------------------------------------

extern "C" void kernel_launch(void* const* d_in, const int* in_sizes, int n_in,
                              void* d_out, int out_size, void* d_ws, size_t ws_size,
                              hipStream_t stream) {
    const float* x   = (const float*)d_in[0];
    const int*   ei  = (const int*)d_in[1];
    const float* Wl1 = (const float*)d_in[2];
    const float* bl1 = (const float*)d_in[3];
    const float* Wr1 = (const float*)d_in[4];
    const float* Wl2 = (const float*)d_in[5];
    const float* bl2 = (const float*)d_in[6];
    const float* Wr2 = (const float*)d_in[7];
    const float* Wl3 = (const float*)d_in[8];
    const float* bl3 = (const float*)d_in[9];
    const float* Wr3 = (const float*)d_in[10];
    float* out = (float*)d_out;

    int N = in_sizes[0] / HID;   // 100000
    int E = in_sizes[1] / 2;     // 1600000
    const int* src = ei;
    const int* dst = ei + E;

    int nsb = (N + SB - 1) / SB;          // 196 sub-buckets
    int PB  = (E + CHUNK - 1) / CHUNK;    // 782 partition wgs
    int sb  = (N + 1023) / 1024;          // 98 scan blocks

    // workspace (~67 MB)
    char* p = (char*)d_ws;
    unsigned short* aggB = (unsigned short*)p; p += (size_t)N * HID * 2;       // 12.8
    unsigned short* bfX  = (unsigned short*)p; p += (size_t)N * HID * 2;       // 12.8
    unsigned short* bf1  = (unsigned short*)p; p += (size_t)N * HID * 2;       // 12.8
    unsigned short* bf2  = (unsigned short*)p; p += (size_t)N * HID * 2;       // 12.8
    int*            csr  = (int*)p;            p += (size_t)E * sizeof(int);   // 6.4
    int*            cnt  = (int*)p;            p += (size_t)N * sizeof(int);
    int*            offs = (int*)p;            p += (size_t)(N + 4) * sizeof(int);
    int*            bsum = (int*)p;            p += 256 * sizeof(int);
    int*            gcnt = (int*)p;            p += MAXSB * sizeof(int);
    unsigned int*   part = (unsigned int*)p;   p += (size_t)MAXSB * SCAP * 4;  // 10.5

    hipMemsetAsync(gcnt, 0, MAXSB * sizeof(int), stream);

    partition_edges<<<PB, 256, 0, stream>>>(src, dst, part, gcnt, E);
    sub_count<<<nsb, 256, 0, stream>>>(part, gcnt, cnt, N);
    scan_partials<<<sb, 256, 0, stream>>>(cnt, bsum, N);
    scan_tops<<<1, 128, 0, stream>>>(bsum, &offs[N], sb, E);
    scan_write<<<sb, 256, 0, stream>>>(cnt, bsum, offs, N);
    sub_fill<<<nsb, 256, 0, stream>>>(part, gcnt, offs, csr, N);

    to_bf16<<<(N * HID / 4 + 255) / 256, 256, 0, stream>>>(x, bfX, N * HID / 4);

    int db = (N + 31) / 32;

    gather_mean<<<2048, 256, 0, stream>>>(bfX, offs, csr, aggB, N);
    dense_cat<<<db, 256, 0, stream>>>(aggB, bfX, Wl1, bl1, Wr1, (float*)nullptr, bf1, N);

    gather_mean<<<2048, 256, 0, stream>>>(bf1, offs, csr, aggB, N);
    dense_cat<<<db, 256, 0, stream>>>(aggB, bf1, Wl2, bl2, Wr2, (float*)nullptr, bf2, N);

    gather_mean<<<2048, 256, 0, stream>>>(bf2, offs, csr, aggB, N);
    dense_cat<<<db, 256, 0, stream>>>(aggB, bf2, Wl3, bl3, Wr3, out, (unsigned short*)nullptr, N);
}